// Round 14
// baseline (294.763 us; speedup 1.0000x reference)
//
#include <hip/hip_runtime.h>
#include <hip/hip_bf16.h>
#include <float.h>

// Problem constants
#define E_  64
#define L_  256
#define D_  768
#define H_  12
#define DH_ 64
#define TD_ 2304     // 3*D
#define NEGV -10000.0f
#define EPS_ 1e-5f

#define GM 16384     // E_*L_
#define GN 2304      // TD_
#define GK 768       // D_

#define RSPLIT 8     // split-K factor for row_logits (over s)
#define NWG_GEMM ((GN/128)*(GM/128))   // 18*128 = 2304, %8==0 -> simple XCD swizzle valid

typedef __attribute__((ext_vector_type(8))) __bf16 bf16x8;
typedef __attribute__((ext_vector_type(4))) float f32x4;
typedef __attribute__((ext_vector_type(8))) unsigned short u16x8;

__device__ __forceinline__ float wred_sum64(float v){
  #pragma unroll
  for (int o = 32; o > 0; o >>= 1) v += __shfl_xor(v, o, 64);
  return v;
}
__device__ __forceinline__ float wred_max64(float v){
  #pragma unroll
  for (int o = 32; o > 0; o >>= 1) v = fmaxf(v, __shfl_xor(v, o, 64));
  return v;
}
__device__ __forceinline__ unsigned short f2bf(float f){
  unsigned int u = __float_as_uint(f);
  u += 0x7FFF + ((u >> 16) & 1);   // round-to-nearest-even
  return (unsigned short)(u >> 16);
}
__device__ __forceinline__ float bf2f(unsigned short s){
  return __uint_as_float(((unsigned int)s) << 16);
}

// fp32 -> bf16, 8 elems/thread, exact grid (n % 2048 == 0)
__global__ __launch_bounds__(256) void f2b_kernel(
    const float* __restrict__ in, unsigned short* __restrict__ out){
  size_t i = ((size_t)blockIdx.x * 256 + threadIdx.x) * 8;
  float4 a = *(const float4*)(in + i);
  float4 b = *(const float4*)(in + i + 4);
  u16x8 o;
  o[0]=f2bf(a.x); o[1]=f2bf(a.y); o[2]=f2bf(a.z); o[3]=f2bf(a.w);
  o[4]=f2bf(b.x); o[5]=f2bf(b.y); o[6]=f2bf(b.z); o[7]=f2bf(b.w);
  *(u16x8*)(out + i) = o;
}

// msum[l] = -10000 * sum_s pm[s,l]
__global__ void masksum_kernel(const int* __restrict__ pm, float* __restrict__ msum){
  int l = threadIdx.x;
  int cnt = 0;
  #pragma unroll
  for (int s = 0; s < E_; ++s) cnt += (pm[s * L_ + l] != 0);
  msum[l] = NEGV * (float)cnt;
}

// C[GM,GN](bf16) = A[GM,GK](bf16) @ W[GN,GK](bf16)^T + bias.
// BK=64 + XOR chunk-swizzle (cloned from the proven row_logits_mfma structure:
// pre-swizzled global source, swizzled ds_read) + bijective XCD swizzle.
__global__ __launch_bounds__(256) void gemm_mfma_nt(
    const unsigned short* __restrict__ A,
    const unsigned short* __restrict__ W,
    const float* __restrict__ bias,
    unsigned short* __restrict__ C){
  __shared__ unsigned short As[128*64] __attribute__((aligned(16)));
  __shared__ unsigned short Bs[128*64] __attribute__((aligned(16)));
  int lin = blockIdx.x;
  int swz = (lin & 7) * (NWG_GEMM / 8) + (lin >> 3);   // T1: contiguous chunk per XCD
  int m0 = (swz / (GN/128)) * 128;
  int n0 = (swz % (GN/128)) * 128;
  int tid = threadIdx.x;
  int lane = tid & 63, wave = tid >> 6;
  int wr = wave >> 1, wc = wave & 1;
  int lanelow = lane & 15, kgrp = lane >> 4;

  f32x4 zero = {0.f, 0.f, 0.f, 0.f};
  f32x4 acc[4][4];
  #pragma unroll
  for (int mf = 0; mf < 4; ++mf)
    #pragma unroll
    for (int nf = 0; nf < 4; ++nf) acc[mf][nf] = zero;

  int cb8 = tid & 7;
  int strow = tid >> 3;   // 0..31

  for (int kt = 0; kt < GK / 64; ++kt){
    int k0 = kt * 64;
    __syncthreads();
    #pragma unroll
    for (int q = 0; q < 4; ++q){
      int row = q * 32 + strow;
      int srcoff = (cb8 * 8) ^ ((row & 7) * 8);       // pre-swizzled source
      unsigned short* ldsA = &As[(q * 256 + wave * 64) * 8];   // wave-uniform base
      unsigned short* ldsB = &Bs[(q * 256 + wave * 64) * 8];
      __builtin_amdgcn_global_load_lds(
        (const __attribute__((address_space(1))) unsigned int*)(A + (size_t)(m0 + row) * GK + k0 + srcoff),
        (__attribute__((address_space(3))) unsigned int*)ldsA, 16, 0, 0);
      __builtin_amdgcn_global_load_lds(
        (const __attribute__((address_space(1))) unsigned int*)(W + (size_t)(n0 + row) * GK + k0 + srcoff),
        (__attribute__((address_space(3))) unsigned int*)ldsB, 16, 0, 0);
    }
    __syncthreads();
    #pragma unroll
    for (int c0 = 0; c0 < 64; c0 += 32){
      bf16x8 af[4], bfr[4];
      #pragma unroll
      for (int mf = 0; mf < 4; ++mf){
        int row = wr * 64 + mf * 16 + lanelow;
        af[mf] = *(const bf16x8*)&As[row * 64 + ((c0 + kgrp * 8) ^ ((row & 7) * 8))];
      }
      #pragma unroll
      for (int nf = 0; nf < 4; ++nf){
        int row = wc * 64 + nf * 16 + lanelow;
        bfr[nf] = *(const bf16x8*)&Bs[row * 64 + ((c0 + kgrp * 8) ^ ((row & 7) * 8))];
      }
      #pragma unroll
      for (int mf = 0; mf < 4; ++mf)
        #pragma unroll
        for (int nf = 0; nf < 4; ++nf)
          acc[mf][nf] = __builtin_amdgcn_mfma_f32_16x16x32_bf16(af[mf], bfr[nf], acc[mf][nf], 0, 0, 0);
    }
  }

  float bv[4];
  #pragma unroll
  for (int nf = 0; nf < 4; ++nf) bv[nf] = bias[n0 + wc * 64 + nf * 16 + lanelow];
  #pragma unroll
  for (int mf = 0; mf < 4; ++mf){
    int rbase = m0 + wr * 64 + mf * 16 + kgrp * 4;
    #pragma unroll
    for (int j = 0; j < 4; ++j){
      unsigned short* crow = C + (size_t)(rbase + j) * GN + n0 + wc * 64 + lanelow;
      #pragma unroll
      for (int nf = 0; nf < 4; ++nf)
        crow[nf * 16] = f2bf(acc[mf][nf][j] + bv[nf]);
    }
  }
}

// rlogp[p,h,i,j] = sum_{s in split p, c} q[s,i,h,c]*k[s,j,h,c]   (bf16 MFMA)
__global__ __launch_bounds__(256) void row_logits_mfma(
    const unsigned short* __restrict__ qkvb, float* __restrict__ rlogp){
  __shared__ unsigned short As[128*64] __attribute__((aligned(16)));
  __shared__ unsigned short Bs[128*64] __attribute__((aligned(16)));
  int p = blockIdx.x;
  int tile = blockIdx.y;
  int h = blockIdx.z;
  int i0 = (tile >> 1) * 128, j0 = (tile & 1) * 128;
  int tid = threadIdx.x;
  int lane = tid & 63, wave = tid >> 6;
  int wr = wave >> 1, wc = wave & 1;
  int lanelow = lane & 15, kgrp = lane >> 4;

  f32x4 zero = {0.f, 0.f, 0.f, 0.f};
  f32x4 acc[4][4];
  #pragma unroll
  for (int mf = 0; mf < 4; ++mf)
    #pragma unroll
    for (int nf = 0; nf < 4; ++nf) acc[mf][nf] = zero;

  int cb8 = tid & 7;
  const unsigned short* qb = qkvb + h * DH_;
  const unsigned short* kb = qkvb + D_ + h * DH_;

  for (int ss = 0; ss < E_ / RSPLIT; ++ss){
    int s = p * (E_ / RSPLIT) + ss;
    size_t sb = (size_t)s * L_ * TD_;
    __syncthreads();
    #pragma unroll
    for (int q = 0; q < 4; ++q){
      int row = q * 32 + (tid >> 3);
      int srcoff = (cb8 * 8) ^ ((row & 7) * 8);
      unsigned short* ldsA = &As[(q * 256 + wave * 64) * 8];
      unsigned short* ldsB = &Bs[(q * 256 + wave * 64) * 8];
      __builtin_amdgcn_global_load_lds(
        (const __attribute__((address_space(1))) unsigned int*)(qb + sb + (size_t)(i0 + row) * TD_ + srcoff),
        (__attribute__((address_space(3))) unsigned int*)ldsA, 16, 0, 0);
      __builtin_amdgcn_global_load_lds(
        (const __attribute__((address_space(1))) unsigned int*)(kb + sb + (size_t)(j0 + row) * TD_ + srcoff),
        (__attribute__((address_space(3))) unsigned int*)ldsB, 16, 0, 0);
    }
    __syncthreads();
    #pragma unroll
    for (int c0 = 0; c0 < 64; c0 += 32){
      bf16x8 af[4], bfr[4];
      #pragma unroll
      for (int mf = 0; mf < 4; ++mf){
        int row = wr * 64 + mf * 16 + lanelow;
        af[mf] = *(const bf16x8*)&As[row * 64 + ((c0 + kgrp * 8) ^ ((row & 7) * 8))];
      }
      #pragma unroll
      for (int nf = 0; nf < 4; ++nf){
        int row = wc * 64 + nf * 16 + lanelow;
        bfr[nf] = *(const bf16x8*)&Bs[row * 64 + ((c0 + kgrp * 8) ^ ((row & 7) * 8))];
      }
      #pragma unroll
      for (int mf = 0; mf < 4; ++mf)
        #pragma unroll
        for (int nf = 0; nf < 4; ++nf)
          acc[mf][nf] = __builtin_amdgcn_mfma_f32_16x16x32_bf16(af[mf], bfr[nf], acc[mf][nf], 0, 0, 0);
    }
  }

  float* outp = rlogp + ((size_t)p * H_ + h) * (L_ * L_);
  #pragma unroll
  for (int mf = 0; mf < 4; ++mf){
    int ibase = i0 + wr * 64 + mf * 16 + kgrp * 4;
    #pragma unroll
    for (int j2 = 0; j2 < 4; ++j2){
      float* orow = outp + (size_t)(ibase + j2) * L_ + j0 + wc * 64 + lanelow;
      #pragma unroll
      for (int nf = 0; nf < 4; ++nf)
        orow[nf * 16] = acc[mf][nf][j2];
    }
  }
}

// softmax over j: sums RSPLIT partials, scale+mask; writes fp32 maps (output) AND bf16 maps
__global__ __launch_bounds__(256) void row_softmax_kernel(
    const float* __restrict__ rlogp, const float* __restrict__ msum,
    float* __restrict__ maps, unsigned short* __restrict__ mapsb){
  int row = blockIdx.x;          // h*256 + i
  int t = threadIdx.x;
  float v = 0.f;
  #pragma unroll
  for (int pp = 0; pp < RSPLIT; ++pp)
    v += rlogp[(size_t)pp * (H_ * L_ * L_) + (size_t)row * L_ + t];
  v = v * (1.0f / 64.0f) + msum[t];
  __shared__ float red[8];
  float m = wred_max64(v);
  int wid = t >> 6;
  if ((t & 63) == 0) red[wid] = m;
  __syncthreads();
  float bm = fmaxf(fmaxf(red[0], red[1]), fmaxf(red[2], red[3]));
  float e = __expf(v - bm);
  float s = wred_sum64(e);
  if ((t & 63) == 0) red[4 + wid] = s;
  __syncthreads();
  float bs = (red[4] + red[5]) + (red[6] + red[7]);
  float p = e / bs;
  maps[(size_t)row * L_ + t] = p;
  mapsb[(size_t)row * L_ + t] = f2bf(p);
}

// VT[s,h,c,j] = V[s,j,h,c]  (bf16, LDS tile transpose, +1-padded rows)
__global__ __launch_bounds__(256) void vtrans_kernel(
    const unsigned short* __restrict__ qkvb, unsigned short* __restrict__ vt){
  __shared__ unsigned short T[64 * 265];
  int s = blockIdx.x, h = blockIdx.y;
  int t = threadIdx.x;
  const unsigned short* vb = qkvb + 2 * D_ + h * DH_;
  int jr = t >> 3, c0 = (t & 7) * 8;
  #pragma unroll
  for (int pass = 0; pass < 8; ++pass){
    int j = pass * 32 + jr;
    u16x8 r = *(const u16x8*)(vb + ((size_t)s * L_ + j) * TD_ + c0);
    #pragma unroll
    for (int e = 0; e < 8; ++e) T[(c0 + e) * 265 + j] = r[e];
  }
  __syncthreads();
  unsigned short* ob = vt + ((size_t)(s * H_ + h) * DH_) * L_;
  int c = t >> 2;
  #pragma unroll
  for (int u = 0; u < 8; ++u){
    int j0 = ((t & 3) + u * 4) * 8;
    u16x8 w;
    #pragma unroll
    for (int e = 0; e < 8; ++e) w[e] = T[c * 265 + j0 + e];
    *(u16x8*)(ob + (size_t)c * L_ + j0) = w;
  }
}

// rowtmp[s,i,h,c] = bf16( x[s,i,h,c] + sum_j mapsb[h,i,j] * VT[s,h,c,j] )   (MFMA)
__global__ __launch_bounds__(256) void row_pv_mfma(
    const unsigned short* __restrict__ mapsb, const unsigned short* __restrict__ vt,
    const float* __restrict__ x, unsigned short* __restrict__ rowtmp){
  __shared__ unsigned short As[256*32] __attribute__((aligned(16)));
  __shared__ unsigned short Bs[64*32] __attribute__((aligned(16)));
  int s = blockIdx.x, h = blockIdx.y;
  int tid = threadIdx.x;
  int lane = tid & 63, wave = tid >> 6;
  int lanelow = lane & 15, kgrp = lane >> 4;

  f32x4 zero = {0.f, 0.f, 0.f, 0.f};
  f32x4 acc[4][4];
  #pragma unroll
  for (int mf = 0; mf < 4; ++mf)
    #pragma unroll
    for (int nf = 0; nf < 4; ++nf) acc[mf][nf] = zero;

  int srow = lane >> 2;
  int kchunk = (lane & 3) * 8;
  const unsigned short* Ag = mapsb + (size_t)h * (L_ * L_) + (size_t)(wave * 64 + srow) * L_ + kchunk;
  const unsigned short* Bg = vt + (((size_t)s * H_ + h) * DH_ + wave * 16 + srow) * L_ + kchunk;
  unsigned short* AsB = &As[(wave * 64) * 32];
  unsigned short* BsB = &Bs[(wave * 16) * 32];

  for (int k0 = 0; k0 < L_; k0 += 32){
    __syncthreads();
    #pragma unroll
    for (int u = 0; u < 4; ++u)
      __builtin_amdgcn_global_load_lds(
        (const __attribute__((address_space(1))) unsigned int*)(Ag + (size_t)u * 16 * L_ + k0),
        (__attribute__((address_space(3))) unsigned int*)(AsB + u * 16 * 32), 16, 0, 0);
    __builtin_amdgcn_global_load_lds(
      (const __attribute__((address_space(1))) unsigned int*)(Bg + k0),
      (__attribute__((address_space(3))) unsigned int*)(BsB), 16, 0, 0);
    __syncthreads();
    bf16x8 af[4], bfr[4];
    #pragma unroll
    for (int mf = 0; mf < 4; ++mf)
      af[mf] = *(const bf16x8*)&As[(wave * 64 + mf * 16 + lanelow) * 32 + kgrp * 8];
    #pragma unroll
    for (int nf = 0; nf < 4; ++nf)
      bfr[nf] = *(const bf16x8*)&Bs[(nf * 16 + lanelow) * 32 + kgrp * 8];
    #pragma unroll
    for (int mf = 0; mf < 4; ++mf)
      #pragma unroll
      for (int nf = 0; nf < 4; ++nf)
        acc[mf][nf] = __builtin_amdgcn_mfma_f32_16x16x32_bf16(af[mf], bfr[nf], acc[mf][nf], 0, 0, 0);
  }

  #pragma unroll
  for (int mf = 0; mf < 4; ++mf){
    int ibase = wave * 64 + mf * 16 + kgrp * 4;
    #pragma unroll
    for (int j2 = 0; j2 < 4; ++j2){
      size_t rb = ((size_t)s * L_ + ibase + j2) * D_ + h * DH_ + lanelow;
      #pragma unroll
      for (int nf = 0; nf < 4; ++nf)
        rowtmp[rb + nf * 16] = f2bf(acc[mf][nf][j2] + x[rb + nf * 16]);
    }
  }
}

// LN1: reads bf16 rowtmp, writes bf16 out1 (feeds gemm2 and the ln2 residual)
__global__ __launch_bounds__(256) void ln1_kernel(
    const unsigned short* __restrict__ a,
    const float* __restrict__ g, const float* __restrict__ be,
    unsigned short* __restrict__ outb){
  int row = blockIdx.x;
  int t = threadIdx.x;
  const unsigned short* pa = a + (size_t)row * D_;
  float v[3];
  float s1 = 0.f, s2 = 0.f;
  #pragma unroll
  for (int u = 0; u < 3; ++u){
    int c = t + u * 256;
    float xv = bf2f(pa[c]);
    v[u] = xv; s1 += xv; s2 += xv * xv;
  }
  s1 = wred_sum64(s1); s2 = wred_sum64(s2);
  __shared__ float red[8];
  int wid = t >> 6;
  if ((t & 63) == 0){ red[wid] = s1; red[4 + wid] = s2; }
  __syncthreads();
  float ts1 = (red[0] + red[1]) + (red[2] + red[3]);
  float ts2 = (red[4] + red[5]) + (red[6] + red[7]);
  float mu = ts1 * (1.0f / D_);
  float var = ts2 * (1.0f / D_) - mu * mu;
  float rs = rsqrtf(var + EPS_);
  #pragma unroll
  for (int u = 0; u < 3; ++u){
    int c = t + u * 256;
    outb[(size_t)row * D_ + c] = f2bf((v[u] - mu) * rs * g[c] + be[c]);
  }
}

// LN2: reads bf16 out1 + bf16 colout, writes fp32 final output
__global__ __launch_bounds__(256) void ln2_kernel(
    const unsigned short* __restrict__ ab,
    const unsigned short* __restrict__ b,
    const float* __restrict__ g, const float* __restrict__ be,
    float* __restrict__ out){
  int row = blockIdx.x;
  int t = threadIdx.x;
  const unsigned short* pa = ab + (size_t)row * D_;
  const unsigned short* pb = b + (size_t)row * D_;
  float v[3];
  float s1 = 0.f, s2 = 0.f;
  #pragma unroll
  for (int u = 0; u < 3; ++u){
    int c = t + u * 256;
    float xv = bf2f(pa[c]) + bf2f(pb[c]);
    v[u] = xv; s1 += xv; s2 += xv * xv;
  }
  s1 = wred_sum64(s1); s2 = wred_sum64(s2);
  __shared__ float red[8];
  int wid = t >> 6;
  if ((t & 63) == 0){ red[wid] = s1; red[4 + wid] = s2; }
  __syncthreads();
  float ts1 = (red[0] + red[1]) + (red[2] + red[3]);
  float ts2 = (red[4] + red[5]) + (red[6] + red[7]);
  float mu = ts1 * (1.0f / D_);
  float var = ts2 * (1.0f / D_) - mu * mu;
  float rs = rsqrtf(var + EPS_);
  #pragma unroll
  for (int u = 0; u < 3; ++u){
    int c = t + u * 256;
    out[(size_t)row * D_ + c] = (v[u] - mu) * rs * g[c] + be[c];
  }
}

// Column attention via MFMA. One block per (l,h); 4 waves, wave w owns i-rows
// [w*16, w*16+16). Writes bf16 colout.
__global__ __launch_bounds__(256) void col_attn_mfma(
    const unsigned short* __restrict__ qkvb, const int* __restrict__ pm,
    unsigned short* __restrict__ colout){
  __shared__ unsigned short Qs[64*64] __attribute__((aligned(16)));
  __shared__ unsigned short Ks[64*64] __attribute__((aligned(16)));
  __shared__ unsigned short Vt[64*64] __attribute__((aligned(16)));
  __shared__ unsigned short Ps[64*64] __attribute__((aligned(16)));
  __shared__ float cmask[64];
  int l = blockIdx.x, h = blockIdx.y;
  int tid = threadIdx.x;
  int lane = tid & 63, wave = tid >> 6;
  int lanelow = lane & 15, kgrp = lane >> 4;

  const unsigned short* qb = qkvb + h * DH_;
  const unsigned short* kb = qkvb + D_ + h * DH_;
  const unsigned short* vb = qkvb + 2 * D_ + h * DH_;

  if (tid < 64) cmask[tid] = (pm[tid * L_ + l] != 0) ? NEGV : 0.f;

  {
    int row = tid >> 3, ch = tid & 7;
    #pragma unroll
    for (int pass = 0; pass < 2; ++pass){
      int r2 = row + pass * 32;
      size_t gbase = ((size_t)r2 * L_ + l) * TD_ + ch * 8;
      u16x8 q8 = *(const u16x8*)(qb + gbase);
      u16x8 k8 = *(const u16x8*)(kb + gbase);
      int dst = r2 * 64 + ((ch ^ (r2 & 7)) * 8);
      *(u16x8*)&Qs[dst] = q8;
      *(u16x8*)&Ks[dst] = k8;
    }
  }
  {
    int jr = tid & 31, ch = tid >> 5;
    #pragma unroll
    for (int pass = 0; pass < 2; ++pass){
      int j = jr + pass * 32;
      u16x8 v8 = *(const u16x8*)(vb + ((size_t)j * L_ + l) * TD_ + ch * 8);
      #pragma unroll
      for (int e = 0; e < 8; ++e){
        int c = ch * 8 + e;
        Vt[c * 64 + (((j >> 3) ^ (c & 7)) * 8) + (j & 7)] = v8[e];
      }
    }
  }
  __syncthreads();

  f32x4 zero = {0.f, 0.f, 0.f, 0.f};
  f32x4 acc[4] = {zero, zero, zero, zero};
  int irow = wave * 16 + lanelow;
  #pragma unroll
  for (int ks = 0; ks < 2; ++ks){
    bf16x8 af = *(const bf16x8*)&Qs[irow * 64 + (((ks * 4 + kgrp) ^ (irow & 7)) * 8)];
    #pragma unroll
    for (int nf = 0; nf < 4; ++nf){
      int jrow = nf * 16 + lanelow;
      bf16x8 bk = *(const bf16x8*)&Ks[jrow * 64 + (((ks * 4 + kgrp) ^ (jrow & 7)) * 8)];
      acc[nf] = __builtin_amdgcn_mfma_f32_16x16x32_bf16(af, bk, acc[nf], 0, 0, 0);
    }
  }
  float cm[4];
  #pragma unroll
  for (int nf = 0; nf < 4; ++nf) cm[nf] = cmask[nf * 16 + lanelow];
  #pragma unroll
  for (int r = 0; r < 4; ++r){
    float pvv[4];
    float m = -FLT_MAX;
    #pragma unroll
    for (int nf = 0; nf < 4; ++nf){
      pvv[nf] = acc[nf][r] * 0.125f + cm[nf];
      m = fmaxf(m, pvv[nf]);
    }
    m = fmaxf(m, __shfl_xor(m, 1, 64));
    m = fmaxf(m, __shfl_xor(m, 2, 64));
    m = fmaxf(m, __shfl_xor(m, 4, 64));
    m = fmaxf(m, __shfl_xor(m, 8, 64));
    float s = 0.f;
    #pragma unroll
    for (int nf = 0; nf < 4; ++nf){ pvv[nf] = __expf(pvv[nf] - m); s += pvv[nf]; }
    s += __shfl_xor(s, 1, 64);
    s += __shfl_xor(s, 2, 64);
    s += __shfl_xor(s, 4, 64);
    s += __shfl_xor(s, 8, 64);
    float inv = 1.0f / s;
    int i = wave * 16 + kgrp * 4 + r;
    #pragma unroll
    for (int nf = 0; nf < 4; ++nf){
      int j = nf * 16 + lanelow;
      Ps[i * 64 + (((j >> 3) ^ (i & 7)) * 8) + (j & 7)] = f2bf(pvv[nf] * inv);
    }
  }
  __syncthreads();

  f32x4 acc2[4] = {zero, zero, zero, zero};
  #pragma unroll
  for (int ks = 0; ks < 2; ++ks){
    bf16x8 pa = *(const bf16x8*)&Ps[irow * 64 + (((ks * 4 + kgrp) ^ (irow & 7)) * 8)];
    #pragma unroll
    for (int nf = 0; nf < 4; ++nf){
      int crow = nf * 16 + lanelow;
      bf16x8 bv = *(const bf16x8*)&Vt[crow * 64 + (((ks * 4 + kgrp) ^ (crow & 7)) * 8)];
      acc2[nf] = __builtin_amdgcn_mfma_f32_16x16x32_bf16(pa, bv, acc2[nf], 0, 0, 0);
    }
  }
  #pragma unroll
  for (int r = 0; r < 4; ++r){
    int i = wave * 16 + kgrp * 4 + r;
    size_t ob = ((size_t)i * L_ + l) * D_ + h * DH_ + lanelow;
    #pragma unroll
    for (int nf = 0; nf < 4; ++nf)
      colout[ob + nf * 16] = f2bf(acc2[nf][r]);
  }
}

extern "C" void kernel_launch(void* const* d_in, const int* in_sizes, int n_in,
                              void* d_out, int out_size, void* d_ws, size_t ws_size,
                              hipStream_t stream){
  (void)in_sizes; (void)n_in; (void)out_size; (void)ws_size;
  const float* x     = (const float*)d_in[0];
  const int*   pm    = (const int*)  d_in[1];
  const float* w_row = (const float*)d_in[2];
  const float* b_row = (const float*)d_in[3];
  const float* w_col = (const float*)d_in[4];
  const float* b_col = (const float*)d_in[5];
  const float* g1    = (const float*)d_in[6];
  const float* be1   = (const float*)d_in[7];
  const float* g2    = (const float*)d_in[8];
  const float* be2   = (const float*)d_in[9];

  float* out  = (float*)d_out;                       // [64,256,768]
  float* maps = out + (size_t)E_ * L_ * D_;          // [12,256,256]

  // ws layout (float offsets) — total 52,494,592 f = 200.3 MiB (< proven 225.8)
  float* F    = (float*)d_ws;
  unsigned short* qkvb = (unsigned short*)F;
  unsigned short* tmpb16 = (unsigned short*)(F + 18874368);  // xb / rowtmp / colout
  unsigned short* out1b = (unsigned short*)(F + 31457280);
  float* msum = F + 37748736;
  float* rlogp = F + 37748992;
  unsigned short* wrb = (unsigned short*)(F + 44040448);
  unsigned short* wcb = (unsigned short*)(F + 44925184);
  unsigned short* mapsb = (unsigned short*)(F + 45809920);
  unsigned short* vtb = (unsigned short*)(F + 46203136);

  const int M = E_ * L_;        // 16384
  const int NX = M * D_;        // 12,582,912
  const int NW = TD_ * D_;      // 1,769,472

  masksum_kernel<<<1, 256, 0, stream>>>(pm, msum);
  f2b_kernel<<<NX / 2048, 256, 0, stream>>>(x, tmpb16);
  f2b_kernel<<<NW / 2048, 256, 0, stream>>>(w_row, wrb);
  f2b_kernel<<<NW / 2048, 256, 0, stream>>>(w_col, wcb);

  gemm_mfma_nt<<<NWG_GEMM, 256, 0, stream>>>(tmpb16, wrb, b_row, qkvb);
  vtrans_kernel<<<dim3(E_, H_), 256, 0, stream>>>(qkvb, vtb);
  row_logits_mfma<<<dim3(RSPLIT, 4, H_), 256, 0, stream>>>(qkvb, rlogp);
  row_softmax_kernel<<<H_ * L_, 256, 0, stream>>>(rlogp, msum, maps, mapsb);
  row_pv_mfma<<<dim3(E_, H_), 256, 0, stream>>>(mapsb, vtb, x, tmpb16);   // rowtmp (bf16)
  ln1_kernel<<<M, 256, 0, stream>>>(tmpb16, g1, be1, out1b);
  gemm_mfma_nt<<<NWG_GEMM, 256, 0, stream>>>(out1b, wcb, b_col, qkvb);
  col_attn_mfma<<<dim3(L_, H_), 256, 0, stream>>>(qkvb, pm, tmpb16);      // colout (bf16)
  ln2_kernel<<<M, 256, 0, stream>>>(out1b, tmpb16, g2, be2, out);
}

// Round 17
// 263.054 us; speedup vs baseline: 1.1205x; 1.1205x over previous
//
#include <hip/hip_runtime.h>
#include <hip/hip_bf16.h>
#include <float.h>

// Problem constants
#define E_  64
#define L_  256
#define D_  768
#define H_  12
#define DH_ 64
#define TD_ 2304     // 3*D
#define NEGV -10000.0f
#define EPS_ 1e-5f

#define GM 16384     // E_*L_
#define GN 2304      // TD_
#define GK 768       // D_

#define RSPLIT 8     // split-K factor for row_logits (over s)
#define NWG_GEMM ((GN/128)*(GM/128))   // 2304, %8==0 -> simple XCD swizzle valid

typedef __attribute__((ext_vector_type(8))) __bf16 bf16x8;
typedef __attribute__((ext_vector_type(4))) float f32x4;
typedef __attribute__((ext_vector_type(8))) unsigned short u16x8;

__device__ __forceinline__ float wred_sum64(float v){
  #pragma unroll
  for (int o = 32; o > 0; o >>= 1) v += __shfl_xor(v, o, 64);
  return v;
}
__device__ __forceinline__ float wred_max64(float v){
  #pragma unroll
  for (int o = 32; o > 0; o >>= 1) v = fmaxf(v, __shfl_xor(v, o, 64));
  return v;
}
__device__ __forceinline__ unsigned short f2bf(float f){
  unsigned int u = __float_as_uint(f);
  u += 0x7FFF + ((u >> 16) & 1);   // round-to-nearest-even
  return (unsigned short)(u >> 16);
}
__device__ __forceinline__ float bf2f(unsigned short s){
  return __uint_as_float(((unsigned int)s) << 16);
}

// fp32 -> bf16, 8 elems/thread, exact grid (n % 2048 == 0)
__global__ __launch_bounds__(256) void f2b_kernel(
    const float* __restrict__ in, unsigned short* __restrict__ out){
  size_t i = ((size_t)blockIdx.x * 256 + threadIdx.x) * 8;
  float4 a = *(const float4*)(in + i);
  float4 b = *(const float4*)(in + i + 4);
  u16x8 o;
  o[0]=f2bf(a.x); o[1]=f2bf(a.y); o[2]=f2bf(a.z); o[3]=f2bf(a.w);
  o[4]=f2bf(b.x); o[5]=f2bf(b.y); o[6]=f2bf(b.z); o[7]=f2bf(b.w);
  *(u16x8*)(out + i) = o;
}

// msum[l] = -10000 * sum_s pm[s,l]
__global__ void masksum_kernel(const int* __restrict__ pm, float* __restrict__ msum){
  int l = threadIdx.x;
  int cnt = 0;
  #pragma unroll
  for (int s = 0; s < E_; ++s) cnt += (pm[s * L_ + l] != 0);
  msum[l] = NEGV * (float)cnt;
}

// C[GM,GN](bf16) = A[GM,GK](bf16) @ W[GN,GK](bf16)^T + bias.
// 512 threads / 8 waves on the 128x128 tile (wave = 64x32 output, acc[4][2])
// to recover occupancy (4 blocks/CU wave-slot bound); BK=64 with the proven
// conflict-free row&7 XOR swizzle (conflicts = 0) and bijective XCD swizzle
// (FETCH 85MB proven). Staging pointers precomputed outside the K-loop.
__global__ __launch_bounds__(512) void gemm_mfma_nt(
    const unsigned short* __restrict__ A,
    const unsigned short* __restrict__ W,
    const float* __restrict__ bias,
    unsigned short* __restrict__ C){
  __shared__ unsigned short As[128*64] __attribute__((aligned(16)));
  __shared__ unsigned short Bs[128*64] __attribute__((aligned(16)));
  int lin = blockIdx.x;
  int swz = (lin & 7) * (NWG_GEMM / 8) + (lin >> 3);   // T1: contiguous chunk per XCD
  int m0 = (swz / (GN/128)) * 128;
  int n0 = (swz % (GN/128)) * 128;
  int tid = threadIdx.x;
  int lane = tid & 63, wave = tid >> 6;      // wave 0..7
  int wr = wave >> 2, wc = wave & 3;         // wr 0..1 (64 rows), wc 0..3 (32 cols)
  int lanelow = lane & 15, kgrp = lane >> 4;

  f32x4 zero = {0.f, 0.f, 0.f, 0.f};
  f32x4 acc[4][2];
  #pragma unroll
  for (int mf = 0; mf < 4; ++mf)
    #pragma unroll
    for (int nf = 0; nf < 2; ++nf) acc[mf][nf] = zero;

  // staging (512 thr, 2 issues each for A,B): issue i covers rows i*64..i*64+63
  // thread t -> row = i*64 + (t>>3), chunk cb8 = t&7, source pre-swizzled.
  int cb8 = tid & 7;
  int strow = tid >> 3;                      // 0..63
  const unsigned short* srcA[2];
  const unsigned short* srcB[2];
  #pragma unroll
  for (int i = 0; i < 2; ++i){
    int row = i * 64 + strow;
    int srcoff = (cb8 * 8) ^ ((row & 7) * 8);
    srcA[i] = A + (size_t)(m0 + row) * GK + srcoff;
    srcB[i] = W + (size_t)(n0 + row) * GK + srcoff;
  }
  // LDS dest: wave-uniform base; lane l lands at base + l*16B (= row-major linear)
  unsigned short* dstA[2];
  unsigned short* dstB[2];
  #pragma unroll
  for (int i = 0; i < 2; ++i){
    dstA[i] = &As[i * 4096 + wave * 512];
    dstB[i] = &Bs[i * 4096 + wave * 512];
  }

  // fragment read offsets
  int arow[4], brow[2];
  #pragma unroll
  for (int mf = 0; mf < 4; ++mf) arow[mf] = wr * 64 + mf * 16 + lanelow;
  #pragma unroll
  for (int nf = 0; nf < 2; ++nf) brow[nf] = wc * 32 + nf * 16 + lanelow;

  for (int kt = 0; kt < GK / 64; ++kt){
    int k0 = kt * 64;
    __syncthreads();
    #pragma unroll
    for (int i = 0; i < 2; ++i){
      __builtin_amdgcn_global_load_lds(
        (const __attribute__((address_space(1))) unsigned int*)(srcA[i] + k0),
        (__attribute__((address_space(3))) unsigned int*)dstA[i], 16, 0, 0);
      __builtin_amdgcn_global_load_lds(
        (const __attribute__((address_space(1))) unsigned int*)(srcB[i] + k0),
        (__attribute__((address_space(3))) unsigned int*)dstB[i], 16, 0, 0);
    }
    __syncthreads();
    #pragma unroll
    for (int c0 = 0; c0 < 64; c0 += 32){
      bf16x8 af[4], bfr[2];
      #pragma unroll
      for (int mf = 0; mf < 4; ++mf)
        af[mf] = *(const bf16x8*)&As[arow[mf] * 64 + ((c0 + kgrp * 8) ^ ((arow[mf] & 7) * 8))];
      #pragma unroll
      for (int nf = 0; nf < 2; ++nf)
        bfr[nf] = *(const bf16x8*)&Bs[brow[nf] * 64 + ((c0 + kgrp * 8) ^ ((brow[nf] & 7) * 8))];
      #pragma unroll
      for (int mf = 0; mf < 4; ++mf)
        #pragma unroll
        for (int nf = 0; nf < 2; ++nf)
          acc[mf][nf] = __builtin_amdgcn_mfma_f32_16x16x32_bf16(af[mf], bfr[nf], acc[mf][nf], 0, 0, 0);
    }
  }

  float bv[2];
  #pragma unroll
  for (int nf = 0; nf < 2; ++nf) bv[nf] = bias[n0 + wc * 32 + nf * 16 + lanelow];
  #pragma unroll
  for (int mf = 0; mf < 4; ++mf){
    int rbase = m0 + wr * 64 + mf * 16 + kgrp * 4;
    #pragma unroll
    for (int j = 0; j < 4; ++j){
      unsigned short* crow = C + (size_t)(rbase + j) * GN + n0 + wc * 32 + lanelow;
      #pragma unroll
      for (int nf = 0; nf < 2; ++nf)
        crow[nf * 16] = f2bf(acc[mf][nf][j] + bv[nf]);
    }
  }
}

// rlogp[p,h,i,j] = sum_{s in split p, c} q[s,i,h,c]*k[s,j,h,c]   (bf16 MFMA)
__global__ __launch_bounds__(256) void row_logits_mfma(
    const unsigned short* __restrict__ qkvb, float* __restrict__ rlogp){
  __shared__ unsigned short As[128*64] __attribute__((aligned(16)));
  __shared__ unsigned short Bs[128*64] __attribute__((aligned(16)));
  int p = blockIdx.x;
  int tile = blockIdx.y;
  int h = blockIdx.z;
  int i0 = (tile >> 1) * 128, j0 = (tile & 1) * 128;
  int tid = threadIdx.x;
  int lane = tid & 63, wave = tid >> 6;
  int wr = wave >> 1, wc = wave & 1;
  int lanelow = lane & 15, kgrp = lane >> 4;

  f32x4 zero = {0.f, 0.f, 0.f, 0.f};
  f32x4 acc[4][4];
  #pragma unroll
  for (int mf = 0; mf < 4; ++mf)
    #pragma unroll
    for (int nf = 0; nf < 4; ++nf) acc[mf][nf] = zero;

  int cb8 = tid & 7;
  const unsigned short* qb = qkvb + h * DH_;
  const unsigned short* kb = qkvb + D_ + h * DH_;

  for (int ss = 0; ss < E_ / RSPLIT; ++ss){
    int s = p * (E_ / RSPLIT) + ss;
    size_t sb = (size_t)s * L_ * TD_;
    __syncthreads();
    #pragma unroll
    for (int q = 0; q < 4; ++q){
      int row = q * 32 + (tid >> 3);
      int srcoff = (cb8 * 8) ^ ((row & 7) * 8);
      unsigned short* ldsA = &As[(q * 256 + wave * 64) * 8];
      unsigned short* ldsB = &Bs[(q * 256 + wave * 64) * 8];
      __builtin_amdgcn_global_load_lds(
        (const __attribute__((address_space(1))) unsigned int*)(qb + sb + (size_t)(i0 + row) * TD_ + srcoff),
        (__attribute__((address_space(3))) unsigned int*)ldsA, 16, 0, 0);
      __builtin_amdgcn_global_load_lds(
        (const __attribute__((address_space(1))) unsigned int*)(kb + sb + (size_t)(j0 + row) * TD_ + srcoff),
        (__attribute__((address_space(3))) unsigned int*)ldsB, 16, 0, 0);
    }
    __syncthreads();
    #pragma unroll
    for (int c0 = 0; c0 < 64; c0 += 32){
      bf16x8 af[4], bfr[4];
      #pragma unroll
      for (int mf = 0; mf < 4; ++mf){
        int row = wr * 64 + mf * 16 + lanelow;
        af[mf] = *(const bf16x8*)&As[row * 64 + ((c0 + kgrp * 8) ^ ((row & 7) * 8))];
      }
      #pragma unroll
      for (int nf = 0; nf < 4; ++nf){
        int row = wc * 64 + nf * 16 + lanelow;
        bfr[nf] = *(const bf16x8*)&Bs[row * 64 + ((c0 + kgrp * 8) ^ ((row & 7) * 8))];
      }
      #pragma unroll
      for (int mf = 0; mf < 4; ++mf)
        #pragma unroll
        for (int nf = 0; nf < 4; ++nf)
          acc[mf][nf] = __builtin_amdgcn_mfma_f32_16x16x32_bf16(af[mf], bfr[nf], acc[mf][nf], 0, 0, 0);
    }
  }

  float* outp = rlogp + ((size_t)p * H_ + h) * (L_ * L_);
  #pragma unroll
  for (int mf = 0; mf < 4; ++mf){
    int ibase = i0 + wr * 64 + mf * 16 + kgrp * 4;
    #pragma unroll
    for (int j2 = 0; j2 < 4; ++j2){
      float* orow = outp + (size_t)(ibase + j2) * L_ + j0 + wc * 64 + lanelow;
      #pragma unroll
      for (int nf = 0; nf < 4; ++nf)
        orow[nf * 16] = acc[mf][nf][j2];
    }
  }
}

// softmax over j: sums RSPLIT partials, scale+mask; writes fp32 maps (output) AND bf16 maps
__global__ __launch_bounds__(256) void row_softmax_kernel(
    const float* __restrict__ rlogp, const float* __restrict__ msum,
    float* __restrict__ maps, unsigned short* __restrict__ mapsb){
  int row = blockIdx.x;          // h*256 + i
  int t = threadIdx.x;
  float v = 0.f;
  #pragma unroll
  for (int pp = 0; pp < RSPLIT; ++pp)
    v += rlogp[(size_t)pp * (H_ * L_ * L_) + (size_t)row * L_ + t];
  v = v * (1.0f / 64.0f) + msum[t];
  __shared__ float red[8];
  float m = wred_max64(v);
  int wid = t >> 6;
  if ((t & 63) == 0) red[wid] = m;
  __syncthreads();
  float bm = fmaxf(fmaxf(red[0], red[1]), fmaxf(red[2], red[3]));
  float e = __expf(v - bm);
  float s = wred_sum64(e);
  if ((t & 63) == 0) red[4 + wid] = s;
  __syncthreads();
  float bs = (red[4] + red[5]) + (red[6] + red[7]);
  float p = e / bs;
  maps[(size_t)row * L_ + t] = p;
  mapsb[(size_t)row * L_ + t] = f2bf(p);
}

// VT[s,h,c,j] = V[s,j,h,c]  (bf16, LDS tile transpose, +1-padded rows)
__global__ __launch_bounds__(256) void vtrans_kernel(
    const unsigned short* __restrict__ qkvb, unsigned short* __restrict__ vt){
  __shared__ unsigned short T[64 * 265];
  int s = blockIdx.x, h = blockIdx.y;
  int t = threadIdx.x;
  const unsigned short* vb = qkvb + 2 * D_ + h * DH_;
  int jr = t >> 3, c0 = (t & 7) * 8;
  #pragma unroll
  for (int pass = 0; pass < 8; ++pass){
    int j = pass * 32 + jr;
    u16x8 r = *(const u16x8*)(vb + ((size_t)s * L_ + j) * TD_ + c0);
    #pragma unroll
    for (int e = 0; e < 8; ++e) T[(c0 + e) * 265 + j] = r[e];
  }
  __syncthreads();
  unsigned short* ob = vt + ((size_t)(s * H_ + h) * DH_) * L_;
  int c = t >> 2;
  #pragma unroll
  for (int u = 0; u < 8; ++u){
    int j0 = ((t & 3) + u * 4) * 8;
    u16x8 w;
    #pragma unroll
    for (int e = 0; e < 8; ++e) w[e] = T[c * 265 + j0 + e];
    *(u16x8*)(ob + (size_t)c * L_ + j0) = w;
  }
}

// rowtmp[s,i,h,c] = bf16( x[s,i,h,c] + sum_j mapsb[h,i,j] * VT[s,h,c,j] )   (MFMA)
__global__ __launch_bounds__(256) void row_pv_mfma(
    const unsigned short* __restrict__ mapsb, const unsigned short* __restrict__ vt,
    const float* __restrict__ x, unsigned short* __restrict__ rowtmp){
  __shared__ unsigned short As[256*32] __attribute__((aligned(16)));
  __shared__ unsigned short Bs[64*32] __attribute__((aligned(16)));
  int s = blockIdx.x, h = blockIdx.y;
  int tid = threadIdx.x;
  int lane = tid & 63, wave = tid >> 6;
  int lanelow = lane & 15, kgrp = lane >> 4;

  f32x4 zero = {0.f, 0.f, 0.f, 0.f};
  f32x4 acc[4][4];
  #pragma unroll
  for (int mf = 0; mf < 4; ++mf)
    #pragma unroll
    for (int nf = 0; nf < 4; ++nf) acc[mf][nf] = zero;

  int srow = lane >> 2;
  int kchunk = (lane & 3) * 8;
  const unsigned short* Ag = mapsb + (size_t)h * (L_ * L_) + (size_t)(wave * 64 + srow) * L_ + kchunk;
  const unsigned short* Bg = vt + (((size_t)s * H_ + h) * DH_ + wave * 16 + srow) * L_ + kchunk;
  unsigned short* AsB = &As[(wave * 64) * 32];
  unsigned short* BsB = &Bs[(wave * 16) * 32];

  for (int k0 = 0; k0 < L_; k0 += 32){
    __syncthreads();
    #pragma unroll
    for (int u = 0; u < 4; ++u)
      __builtin_amdgcn_global_load_lds(
        (const __attribute__((address_space(1))) unsigned int*)(Ag + (size_t)u * 16 * L_ + k0),
        (__attribute__((address_space(3))) unsigned int*)(AsB + u * 16 * 32), 16, 0, 0);
    __builtin_amdgcn_global_load_lds(
      (const __attribute__((address_space(1))) unsigned int*)(Bg + k0),
      (__attribute__((address_space(3))) unsigned int*)(BsB), 16, 0, 0);
    __syncthreads();
    bf16x8 af[4], bfr[4];
    #pragma unroll
    for (int mf = 0; mf < 4; ++mf)
      af[mf] = *(const bf16x8*)&As[(wave * 64 + mf * 16 + lanelow) * 32 + kgrp * 8];
    #pragma unroll
    for (int nf = 0; nf < 4; ++nf)
      bfr[nf] = *(const bf16x8*)&Bs[(nf * 16 + lanelow) * 32 + kgrp * 8];
    #pragma unroll
    for (int mf = 0; mf < 4; ++mf)
      #pragma unroll
      for (int nf = 0; nf < 4; ++nf)
        acc[mf][nf] = __builtin_amdgcn_mfma_f32_16x16x32_bf16(af[mf], bfr[nf], acc[mf][nf], 0, 0, 0);
  }

  #pragma unroll
  for (int mf = 0; mf < 4; ++mf){
    int ibase = wave * 64 + mf * 16 + kgrp * 4;
    #pragma unroll
    for (int j2 = 0; j2 < 4; ++j2){
      size_t rb = ((size_t)s * L_ + ibase + j2) * D_ + h * DH_ + lanelow;
      #pragma unroll
      for (int nf = 0; nf < 4; ++nf)
        rowtmp[rb + nf * 16] = f2bf(acc[mf][nf][j2] + x[rb + nf * 16]);
    }
  }
}

// LN1: reads bf16 rowtmp, writes bf16 out1 (feeds gemm2 and the ln2 residual)
__global__ __launch_bounds__(256) void ln1_kernel(
    const unsigned short* __restrict__ a,
    const float* __restrict__ g, const float* __restrict__ be,
    unsigned short* __restrict__ outb){
  int row = blockIdx.x;
  int t = threadIdx.x;
  const unsigned short* pa = a + (size_t)row * D_;
  float v[3];
  float s1 = 0.f, s2 = 0.f;
  #pragma unroll
  for (int u = 0; u < 3; ++u){
    int c = t + u * 256;
    float xv = bf2f(pa[c]);
    v[u] = xv; s1 += xv; s2 += xv * xv;
  }
  s1 = wred_sum64(s1); s2 = wred_sum64(s2);
  __shared__ float red[8];
  int wid = t >> 6;
  if ((t & 63) == 0){ red[wid] = s1; red[4 + wid] = s2; }
  __syncthreads();
  float ts1 = (red[0] + red[1]) + (red[2] + red[3]);
  float ts2 = (red[4] + red[5]) + (red[6] + red[7]);
  float mu = ts1 * (1.0f / D_);
  float var = ts2 * (1.0f / D_) - mu * mu;
  float rs = rsqrtf(var + EPS_);
  #pragma unroll
  for (int u = 0; u < 3; ++u){
    int c = t + u * 256;
    outb[(size_t)row * D_ + c] = f2bf((v[u] - mu) * rs * g[c] + be[c]);
  }
}

// LN2: reads bf16 out1 + bf16 colout, writes fp32 final output
__global__ __launch_bounds__(256) void ln2_kernel(
    const unsigned short* __restrict__ ab,
    const unsigned short* __restrict__ b,
    const float* __restrict__ g, const float* __restrict__ be,
    float* __restrict__ out){
  int row = blockIdx.x;
  int t = threadIdx.x;
  const unsigned short* pa = ab + (size_t)row * D_;
  const unsigned short* pb = b + (size_t)row * D_;
  float v[3];
  float s1 = 0.f, s2 = 0.f;
  #pragma unroll
  for (int u = 0; u < 3; ++u){
    int c = t + u * 256;
    float xv = bf2f(pa[c]) + bf2f(pb[c]);
    v[u] = xv; s1 += xv; s2 += xv * xv;
  }
  s1 = wred_sum64(s1); s2 = wred_sum64(s2);
  __shared__ float red[8];
  int wid = t >> 6;
  if ((t & 63) == 0){ red[wid] = s1; red[4 + wid] = s2; }
  __syncthreads();
  float ts1 = (red[0] + red[1]) + (red[2] + red[3]);
  float ts2 = (red[4] + red[5]) + (red[6] + red[7]);
  float mu = ts1 * (1.0f / D_);
  float var = ts2 * (1.0f / D_) - mu * mu;
  float rs = rsqrtf(var + EPS_);
  #pragma unroll
  for (int u = 0; u < 3; ++u){
    int c = t + u * 256;
    out[(size_t)row * D_ + c] = (v[u] - mu) * rs * g[c] + be[c];
  }
}

// Column attention via MFMA. One block per (l,h); 4 waves, wave w owns i-rows
// [w*16, w*16+16). Writes bf16 colout.
__global__ __launch_bounds__(256) void col_attn_mfma(
    const unsigned short* __restrict__ qkvb, const int* __restrict__ pm,
    unsigned short* __restrict__ colout){
  __shared__ unsigned short Qs[64*64] __attribute__((aligned(16)));
  __shared__ unsigned short Ks[64*64] __attribute__((aligned(16)));
  __shared__ unsigned short Vt[64*64] __attribute__((aligned(16)));
  __shared__ unsigned short Ps[64*64] __attribute__((aligned(16)));
  __shared__ float cmask[64];
  int l = blockIdx.x, h = blockIdx.y;
  int tid = threadIdx.x;
  int lane = tid & 63, wave = tid >> 6;
  int lanelow = lane & 15, kgrp = lane >> 4;

  const unsigned short* qb = qkvb + h * DH_;
  const unsigned short* kb = qkvb + D_ + h * DH_;
  const unsigned short* vb = qkvb + 2 * D_ + h * DH_;

  if (tid < 64) cmask[tid] = (pm[tid * L_ + l] != 0) ? NEGV : 0.f;

  {
    int row = tid >> 3, ch = tid & 7;
    #pragma unroll
    for (int pass = 0; pass < 2; ++pass){
      int r2 = row + pass * 32;
      size_t gbase = ((size_t)r2 * L_ + l) * TD_ + ch * 8;
      u16x8 q8 = *(const u16x8*)(qb + gbase);
      u16x8 k8 = *(const u16x8*)(kb + gbase);
      int dst = r2 * 64 + ((ch ^ (r2 & 7)) * 8);
      *(u16x8*)&Qs[dst] = q8;
      *(u16x8*)&Ks[dst] = k8;
    }
  }
  {
    int jr = tid & 31, ch = tid >> 5;
    #pragma unroll
    for (int pass = 0; pass < 2; ++pass){
      int j = jr + pass * 32;
      u16x8 v8 = *(const u16x8*)(vb + ((size_t)j * L_ + l) * TD_ + ch * 8);
      #pragma unroll
      for (int e = 0; e < 8; ++e){
        int c = ch * 8 + e;
        Vt[c * 64 + (((j >> 3) ^ (c & 7)) * 8) + (j & 7)] = v8[e];
      }
    }
  }
  __syncthreads();

  f32x4 zero = {0.f, 0.f, 0.f, 0.f};
  f32x4 acc[4] = {zero, zero, zero, zero};
  int irow = wave * 16 + lanelow;
  #pragma unroll
  for (int ks = 0; ks < 2; ++ks){
    bf16x8 af = *(const bf16x8*)&Qs[irow * 64 + (((ks * 4 + kgrp) ^ (irow & 7)) * 8)];
    #pragma unroll
    for (int nf = 0; nf < 4; ++nf){
      int jrow = nf * 16 + lanelow;
      bf16x8 bk = *(const bf16x8*)&Ks[jrow * 64 + (((ks * 4 + kgrp) ^ (jrow & 7)) * 8)];
      acc[nf] = __builtin_amdgcn_mfma_f32_16x16x32_bf16(af, bk, acc[nf], 0, 0, 0);
    }
  }
  float cm[4];
  #pragma unroll
  for (int nf = 0; nf < 4; ++nf) cm[nf] = cmask[nf * 16 + lanelow];
  #pragma unroll
  for (int r = 0; r < 4; ++r){
    float pvv[4];
    float m = -FLT_MAX;
    #pragma unroll
    for (int nf = 0; nf < 4; ++nf){
      pvv[nf] = acc[nf][r] * 0.125f + cm[nf];
      m = fmaxf(m, pvv[nf]);
    }
    m = fmaxf(m, __shfl_xor(m, 1, 64));
    m = fmaxf(m, __shfl_xor(m, 2, 64));
    m = fmaxf(m, __shfl_xor(m, 4, 64));
    m = fmaxf(m, __shfl_xor(m, 8, 64));
    float s = 0.f;
    #pragma unroll
    for (int nf = 0; nf < 4; ++nf){ pvv[nf] = __expf(pvv[nf] - m); s += pvv[nf]; }
    s += __shfl_xor(s, 1, 64);
    s += __shfl_xor(s, 2, 64);
    s += __shfl_xor(s, 4, 64);
    s += __shfl_xor(s, 8, 64);
    float inv = 1.0f / s;
    int i = wave * 16 + kgrp * 4 + r;
    #pragma unroll
    for (int nf = 0; nf < 4; ++nf){
      int j = nf * 16 + lanelow;
      Ps[i * 64 + (((j >> 3) ^ (i & 7)) * 8) + (j & 7)] = f2bf(pvv[nf] * inv);
    }
  }
  __syncthreads();

  f32x4 acc2[4] = {zero, zero, zero, zero};
  #pragma unroll
  for (int ks = 0; ks < 2; ++ks){
    bf16x8 pa = *(const bf16x8*)&Ps[irow * 64 + (((ks * 4 + kgrp) ^ (irow & 7)) * 8)];
    #pragma unroll
    for (int nf = 0; nf < 4; ++nf){
      int crow = nf * 16 + lanelow;
      bf16x8 bv = *(const bf16x8*)&Vt[crow * 64 + (((ks * 4 + kgrp) ^ (crow & 7)) * 8)];
      acc2[nf] = __builtin_amdgcn_mfma_f32_16x16x32_bf16(pa, bv, acc2[nf], 0, 0, 0);
    }
  }
  #pragma unroll
  for (int r = 0; r < 4; ++r){
    int i = wave * 16 + kgrp * 4 + r;
    size_t ob = ((size_t)i * L_ + l) * D_ + h * DH_ + lanelow;
    #pragma unroll
    for (int nf = 0; nf < 4; ++nf)
      colout[ob + nf * 16] = f2bf(acc2[nf][r]);
  }
}

extern "C" void kernel_launch(void* const* d_in, const int* in_sizes, int n_in,
                              void* d_out, int out_size, void* d_ws, size_t ws_size,
                              hipStream_t stream){
  (void)in_sizes; (void)n_in; (void)out_size; (void)ws_size;
  const float* x     = (const float*)d_in[0];
  const int*   pm    = (const int*)  d_in[1];
  const float* w_row = (const float*)d_in[2];
  const float* b_row = (const float*)d_in[3];
  const float* w_col = (const float*)d_in[4];
  const float* b_col = (const float*)d_in[5];
  const float* g1    = (const float*)d_in[6];
  const float* be1   = (const float*)d_in[7];
  const float* g2    = (const float*)d_in[8];
  const float* be2   = (const float*)d_in[9];

  float* out  = (float*)d_out;                       // [64,256,768]
  float* maps = out + (size_t)E_ * L_ * D_;          // [12,256,256]

  // ws layout (float offsets) — total 52,494,592 f = 200.3 MiB (< proven 225.8)
  float* F    = (float*)d_ws;
  unsigned short* qkvb = (unsigned short*)F;
  unsigned short* tmpb16 = (unsigned short*)(F + 18874368);  // xb / rowtmp / colout
  unsigned short* out1b = (unsigned short*)(F + 31457280);
  float* msum = F + 37748736;
  float* rlogp = F + 37748992;
  unsigned short* wrb = (unsigned short*)(F + 44040448);
  unsigned short* wcb = (unsigned short*)(F + 44925184);
  unsigned short* mapsb = (unsigned short*)(F + 45809920);
  unsigned short* vtb = (unsigned short*)(F + 46203136);

  const int M = E_ * L_;        // 16384
  const int NX = M * D_;        // 12,582,912
  const int NW = TD_ * D_;      // 1,769,472

  masksum_kernel<<<1, 256, 0, stream>>>(pm, msum);
  f2b_kernel<<<NX / 2048, 256, 0, stream>>>(x, tmpb16);
  f2b_kernel<<<NW / 2048, 256, 0, stream>>>(w_row, wrb);
  f2b_kernel<<<NW / 2048, 256, 0, stream>>>(w_col, wcb);

  gemm_mfma_nt<<<NWG_GEMM, 512, 0, stream>>>(tmpb16, wrb, b_row, qkvb);
  vtrans_kernel<<<dim3(E_, H_), 256, 0, stream>>>(qkvb, vtb);
  row_logits_mfma<<<dim3(RSPLIT, 4, H_), 256, 0, stream>>>(qkvb, rlogp);
  row_softmax_kernel<<<H_ * L_, 256, 0, stream>>>(rlogp, msum, maps, mapsb);
  row_pv_mfma<<<dim3(E_, H_), 256, 0, stream>>>(mapsb, vtb, x, tmpb16);   // rowtmp (bf16)
  ln1_kernel<<<M, 256, 0, stream>>>(tmpb16, g1, be1, out1b);
  gemm_mfma_nt<<<NWG_GEMM, 512, 0, stream>>>(out1b, wcb, b_col, qkvb);
  col_attn_mfma<<<dim3(L_, H_), 256, 0, stream>>>(qkvb, pm, tmpb16);      // colout (bf16)
  ln2_kernel<<<M, 256, 0, stream>>>(out1b, tmpb16, g2, be2, out);
}